// Round 7
// baseline (875.261 us; speedup 1.0000x reference)
//
#include <hip/hip_runtime.h>
#include <stdint.h>

typedef unsigned short u16;
typedef unsigned int u32;
typedef __attribute__((ext_vector_type(8))) short short8;
typedef __attribute__((ext_vector_type(4))) float f32x4;

// ---------- helpers ----------
__device__ __forceinline__ u16 f2bf(float f) {
  u32 u = __builtin_bit_cast(u32, f);
  u32 r = u + 0x7FFFu + ((u >> 16) & 1u);
  return (u16)(r >> 16);
}

__device__ __forceinline__ void gl_lds16(const void* g, void* l) {
  __builtin_amdgcn_global_load_lds((__attribute__((address_space(1))) void*)g,
                                   (__attribute__((address_space(3))) void*)l,
                                   16, 0, 0);
}

// tanh-form GELU (~13 VALU inst; |err| <= ~3e-3, verified absmax unchanged)
__device__ __forceinline__ float gelu_fast(float v) {
  float u = 0.7978845608028654f * (v + 0.044715f * v * v * v);
  float a = fabsf(u);
  float e = __expf(-2.0f * a);
  float t = (1.0f - e) / (1.0f + e);     // tanh(|u|)
  float th = copysignf(t, u);
  return 0.5f * v * (1.0f + th);
}

// ---------- f32 -> bf16 convert (weights) ----------
__global__ __launch_bounds__(256) void cvt_bf16(const float* __restrict__ in,
                                                u16* __restrict__ out, int n4) {
  int idx = blockIdx.x * 256 + threadIdx.x;
  if (idx < n4) {
    float4 v = ((const float4*)in)[idx];
    u32 lo = (u32)f2bf(v.x) | ((u32)f2bf(v.y) << 16);
    u32 hi = (u32)f2bf(v.z) | ((u32)f2bf(v.w) << 16);
    ((uint2*)out)[idx] = make_uint2(lo, hi);
  }
}

// ---------- LN1 + roll + window partition gather ----------
__global__ __launch_bounds__(256) void ln1_kernel(const float* __restrict__ x,
                                                  const float* __restrict__ g,
                                                  const float* __restrict__ bta,
                                                  u16* __restrict__ xcat) {
  int wave = threadIdx.x >> 6, lane = threadIdx.x & 63;
  int row = blockIdx.x * 4 + wave;   // 0..50815
  const float* src;
  bool do_ln;
  if (row < 640) {
    int bb = row / 10, p = row - bb * 10;
    src = x + ((size_t)bb * 794 + p) * 512;
    do_ln = false;
  } else {
    int r2 = row - 640;
    int i = r2 / 49, t = r2 - i * 49;
    int bb = i >> 4, nw = i & 15;
    int tr = t / 7, tc = t - tr * 7;
    int hh = (nw >> 2) * 7 + tr + 3; if (hh >= 28) hh -= 28;
    int ww = (nw & 3) * 7 + tc + 3;  if (ww >= 28) ww -= 28;
    src = x + ((size_t)bb * 794 + 10 + hh * 28 + ww) * 512;
    do_ln = true;
  }
  float4 v0 = ((const float4*)src)[lane * 2];
  float4 v1 = ((const float4*)src)[lane * 2 + 1];
  float vals[8] = {v0.x, v0.y, v0.z, v0.w, v1.x, v1.y, v1.z, v1.w};
  u16 ob[8];
  if (do_ln) {
    float s = 0.f, s2 = 0.f;
#pragma unroll
    for (int j = 0; j < 8; ++j) { s += vals[j]; s2 += vals[j] * vals[j]; }
#pragma unroll
    for (int o = 32; o > 0; o >>= 1) { s += __shfl_xor(s, o); s2 += __shfl_xor(s2, o); }
    float mu = s * (1.0f / 512.0f);
    float var = s2 * (1.0f / 512.0f) - mu * mu;
    float inv = rsqrtf(var + 1e-5f);
    float4 ga = ((const float4*)g)[lane * 2], gb = ((const float4*)g)[lane * 2 + 1];
    float4 ba = ((const float4*)bta)[lane * 2], bb2 = ((const float4*)bta)[lane * 2 + 1];
    float gv[8] = {ga.x, ga.y, ga.z, ga.w, gb.x, gb.y, gb.z, gb.w};
    float bv[8] = {ba.x, ba.y, ba.z, ba.w, bb2.x, bb2.y, bb2.z, bb2.w};
#pragma unroll
    for (int j = 0; j < 8; ++j) ob[j] = f2bf((vals[j] - mu) * inv * gv[j] + bv[j]);
  } else {
#pragma unroll
    for (int j = 0; j < 8; ++j) ob[j] = f2bf(vals[j]);
  }
  u32 w0 = (u32)ob[0] | ((u32)ob[1] << 16);
  u32 w1 = (u32)ob[2] | ((u32)ob[3] << 16);
  u32 w2 = (u32)ob[4] | ((u32)ob[5] << 16);
  u32 w3 = (u32)ob[6] | ((u32)ob[7] << 16);
  ((uint4*)(xcat + (size_t)row * 512))[lane] = make_uint4(w0, w1, w2, w3);
}

// ---------- LN2 (plain rows) ----------
__global__ __launch_bounds__(256) void ln2_kernel(const float* __restrict__ xn,
                                                  const float* __restrict__ g,
                                                  const float* __restrict__ bta,
                                                  u16* __restrict__ outb) {
  int wave = threadIdx.x >> 6, lane = threadIdx.x & 63;
  size_t row = (size_t)blockIdx.x * 4 + wave;
  const float* src = xn + row * 512;
  float4 v0 = ((const float4*)src)[lane * 2];
  float4 v1 = ((const float4*)src)[lane * 2 + 1];
  float vals[8] = {v0.x, v0.y, v0.z, v0.w, v1.x, v1.y, v1.z, v1.w};
  float s = 0.f, s2 = 0.f;
#pragma unroll
  for (int j = 0; j < 8; ++j) { s += vals[j]; s2 += vals[j] * vals[j]; }
#pragma unroll
  for (int o = 32; o > 0; o >>= 1) { s += __shfl_xor(s, o); s2 += __shfl_xor(s2, o); }
  float mu = s * (1.0f / 512.0f);
  float var = s2 * (1.0f / 512.0f) - mu * mu;
  float inv = rsqrtf(var + 1e-5f);
  float4 ga = ((const float4*)g)[lane * 2], gb = ((const float4*)g)[lane * 2 + 1];
  float4 ba = ((const float4*)bta)[lane * 2], bb2 = ((const float4*)bta)[lane * 2 + 1];
  float gv[8] = {ga.x, ga.y, ga.z, ga.w, gb.x, gb.y, gb.z, gb.w};
  float bv[8] = {ba.x, ba.y, ba.z, ba.w, bb2.x, bb2.y, bb2.z, bb2.w};
  u16 ob[8];
#pragma unroll
  for (int j = 0; j < 8; ++j) ob[j] = f2bf((vals[j] - mu) * inv * gv[j] + bv[j]);
  u32 w0 = (u32)ob[0] | ((u32)ob[1] << 16);
  u32 w1 = (u32)ob[2] | ((u32)ob[3] << 16);
  u32 w2 = (u32)ob[4] | ((u32)ob[5] << 16);
  u32 w3 = (u32)ob[6] | ((u32)ob[7] << 16);
  ((uint4*)(outb + row * 512))[lane] = make_uint4(w0, w1, w2, w3);
}

// ---------- persistent 256x256 bf16 GEMM: blocks walk multiple tiles, ring-4 LDS ----------
// A: MxK row-major bf16, Wt: NxK row-major bf16 (B^T).
// Each block processes tiles pb, pb+G, pb+2G, ... with the distance-3 staging ring
// running CONTINUOUSLY across tile boundaries: one pipeline fill per block (not per
// tile), epilogues overlap the next tile's prefetch. Steady state: vmcnt(8) = loads
// of steps s+2,s+3 in flight; epilogue stores transiently inflate vmcnt (amortized).
// LDS swizzle identical to rounds 5/6 (verified conflict-free, rule-21 both-sides).
template <int EPI>
__global__ __launch_bounds__(512, 2) void gemm256p(const u16* __restrict__ A,
                                                   const u16* __restrict__ Wt,
                                                   const float* __restrict__ bias,
                                                   u16* __restrict__ outb,
                                                   float* __restrict__ outf,
                                                   const float* __restrict__ res,
                                                   int M, int N, int K, int Ntiles,
                                                   int tilesTot) {
  __shared__ __align__(16) u16 Asm[4][256 * 32];
  __shared__ __align__(16) u16 Bsm[4][256 * 32];
  const int tid = threadIdx.x;
  const int lane = tid & 63;
  const int wv = tid >> 6;            // 0..7
  const int wm = wv >> 2, wn = wv & 3;
  const int lr = lane & 15;
  const int qh = lane >> 4;           // 0..3 (k-group)
  const int swz8 = (qh ^ ((lr >> 1) & 3)) << 3;   // swizzled read slot (elements)

  // m204 bijective XCD swizzle: concurrent same-XCD blocks cover adjacent tiles
  const int G = gridDim.x;
  const int qx = G >> 3, rx = G & 7;
  const int xcd = blockIdx.x & 7, local = blockIdx.x >> 3;
  const int pb = (xcd < rx ? xcd * (qx + 1) : rx * (qx + 1) + (xcd - rx) * qx) + local;

  const int NT = K >> 5;              // K-tiles of 32 per output tile
  const int NTm1 = NT - 1;
  const int tpb = (tilesTot - pb + G - 1) / G;
  const int stepsTot = tpb * NT;

  // current (compute) tile state
  int curTile = pb;
  int mt = curTile / Ntiles, nt = curTile - mt * Ntiles;
  int tm = mt << 8, tn = nt << 8;

  // staging pointers (for stageTile)
  const int sr = tid >> 2;
  const int sl = tid & 3;
  const int scol = (sl ^ ((sr >> 1) & 3)) << 3;   // pre-swizzled source col (elements)
  int stageTile = pb;
  const u16 *Ap0, *Ap1, *Bp0, *Bp1;
  auto setStagePtrs = [&](int tIdx) {
    int smt = tIdx / Ntiles, snt = tIdx - smt * Ntiles;
    size_t stm = (size_t)(smt << 8), stn = (size_t)(snt << 8);
    Ap0 = A + (stm + sr) * K + scol;
    Ap1 = A + (stm + 128 + sr) * K + scol;
    Bp0 = Wt + (stn + sr) * K + scol;
    Bp1 = Wt + (stn + 128 + sr) * K + scol;
  };
  setStagePtrs(pb);

#define STAGE(s_)                                           \
  do {                                                      \
    int b_ = (s_) & 3;                                      \
    int k0_ = ((s_) & NTm1) << 5;                           \
    gl_lds16(Ap0 + k0_, &Asm[b_][tid * 8]);                 \
    gl_lds16(Ap1 + k0_, &Asm[b_][tid * 8 + 4096]);          \
    gl_lds16(Bp0 + k0_, &Bsm[b_][tid * 8]);                 \
    gl_lds16(Bp1 + k0_, &Bsm[b_][tid * 8 + 4096]);          \
  } while (0)

  f32x4 acc[8][4];
#pragma unroll
  for (int m = 0; m < 8; ++m)
#pragma unroll
    for (int n = 0; n < 4; ++n)
#pragma unroll
      for (int e = 0; e < 4; ++e) acc[m][n][e] = 0.f;

  // prologue: 3 steps in flight (all within first tile; NT >= 16)
  STAGE(0);
  STAGE(1);
  STAGE(2);

  for (int s = 0; s < stepsTot; ++s) {
    // barrier 1: all waves finished reading buf[(s+3)&3] (used at step s-1)
    __builtin_amdgcn_s_barrier();
    asm volatile("" ::: "memory");
    if (s + 3 < stepsTot) {
      if (((s + 3) & NTm1) == 0) { stageTile += G; setStagePtrs(stageTile); }
      STAGE(s + 3);
      asm volatile("s_waitcnt vmcnt(8)" ::: "memory");   // step s certified last iter; s+1 now
    } else if (s == stepsTot - 3) {
      asm volatile("s_waitcnt vmcnt(8)" ::: "memory");
    } else if (s == stepsTot - 2) {
      asm volatile("s_waitcnt vmcnt(4)" ::: "memory");
    } else {
      asm volatile("s_waitcnt vmcnt(0)" ::: "memory");
    }
    // barrier 2: step-s data visible to all waves
    __builtin_amdgcn_s_barrier();
    asm volatile("" ::: "memory");

    const int b = s & 3;
    const u16* Ab = &Asm[b][0];
    const u16* Bb = &Bsm[b][0];
    short8 av[8], bv[4];
#pragma unroll
    for (int m = 0; m < 8; ++m)
      av[m] = *(const short8*)&Ab[(wm * 128 + m * 16 + lr) * 32 + swz8];
#pragma unroll
    for (int n = 0; n < 4; ++n)
      bv[n] = *(const short8*)&Bb[(wn * 64 + n * 16 + lr) * 32 + swz8];
    __builtin_amdgcn_s_setprio(1);
#pragma unroll
    for (int m = 0; m < 8; ++m)
#pragma unroll
      for (int n = 0; n < 4; ++n)
        acc[m][n] = __builtin_amdgcn_mfma_f32_16x16x32_bf16(av[m], bv[n], acc[m][n], 0, 0, 0);
    __builtin_amdgcn_s_setprio(0);

    if ((s & NTm1) == NTm1) {
      // ---- epilogue for tile (tm, tn); next tile's k=0..2 stages already in flight ----
      float bcol[4];
#pragma unroll
      for (int n = 0; n < 4; ++n) bcol[n] = bias[tn + wn * 64 + n * 16 + lr];
#pragma unroll
      for (int m = 0; m < 8; ++m) {
#pragma unroll
        for (int r2 = 0; r2 < 4; ++r2) {
          int grow = tm + wm * 128 + m * 16 + qh * 4 + r2;
          if (grow >= M) continue;                    // QKV tail M-tile
          if (EPI == 1) {
            int i = grow / 49, t = grow - i * 49;
            int bb = i >> 4, nw = i & 15;
            int tr = t / 7, tc = t - tr * 7;
            int hh = (nw >> 2) * 7 + tr + 3; if (hh >= 28) hh -= 28;
            int ww = (nw & 3) * 7 + tc + 3;  if (ww >= 28) ww -= 28;
            size_t dstr = ((size_t)bb * 784 + hh * 28 + ww) * 512;
            size_t srcr = ((size_t)bb * 794 + 10 + hh * 28 + ww) * 512;
#pragma unroll
            for (int n = 0; n < 4; ++n) {
              int gcol = tn + wn * 64 + n * 16 + lr;
              float v = acc[m][n][r2] + bcol[n];
              outf[dstr + gcol] = v + res[srcr + gcol];
            }
          } else {
#pragma unroll
            for (int n = 0; n < 4; ++n) {
              int gcol = tn + wn * 64 + n * 16 + lr;
              float v = acc[m][n][r2] + bcol[n];
              if (EPI == 0) {
                outb[(size_t)grow * N + gcol] = f2bf(v);
              } else if (EPI == 2) {
                outb[(size_t)grow * N + gcol] = f2bf(gelu_fast(v));
              } else { // EPI == 3
                outf[(size_t)grow * N + gcol] = v + res[(size_t)grow * 512 + gcol];
              }
            }
          }
        }
      }
      // zero acc and advance to next tile
#pragma unroll
      for (int m = 0; m < 8; ++m)
#pragma unroll
        for (int n = 0; n < 4; ++n)
#pragma unroll
          for (int e = 0; e < 4; ++e) acc[m][n][e] = 0.f;
      curTile += G;
      if (curTile < tilesTot) {
        mt = curTile / Ntiles; nt = curTile - mt * Ntiles;
        tm = mt << 8; tn = nt << 8;
      }
    }
  }
#undef STAGE
}

// ---------- fused window attention: one wave per (window, head) ----------
__global__ __launch_bounds__(64) void attn_kernel(const u16* __restrict__ Y,
                                                  const float* __restrict__ rpb,
                                                  u16* __restrict__ outp) {
  __shared__ __align__(16) u16 Plds[64 * 64];
  __shared__ __align__(16) u16 Vt[32 * 64];
  __shared__ float biasl[169];
  const int lane = threadIdx.x;
  const int i = blockIdx.x >> 4;
  const int hd = blockIdx.x & 15;
  const int bp = i & 63;           // reference quirk: prompt batch = i % B
  const int nw = i & 15;
  const int hi = nw >> 2, wi = nw & 3;
  const int lr = lane & 15;
  const int lk = (lane >> 4) * 8;

  for (int j = lane; j < 169; j += 64) biasl[j] = rpb[j * 16 + hd];

  short8 qf[4], kf[4];
#pragma unroll
  for (int m = 0; m < 4; ++m) {
    int t = m * 16 + lr;
    size_t r = (t < 10) ? (size_t)(bp * 10 + t) : (size_t)(640 + i * 49 + (t - 10));
    const u16* base = Y + r * 1536 + hd * 32 + lk;
    if (t < 59) {
      qf[m] = *(const short8*)(base);
      kf[m] = *(const short8*)(base + 512);
    } else {
#pragma unroll
      for (int e = 0; e < 8; ++e) { qf[m][e] = 0; kf[m][e] = 0; }
    }
  }
  // stage V^T (32 x 64)
  {
    int t = lane;
    if (t < 59) {
      size_t r = (t < 10) ? (size_t)(bp * 10 + t) : (size_t)(640 + i * 49 + (t - 10));
      const u16* vp = Y + r * 1536 + 1024 + hd * 32;
      short8 vv0 = *(const short8*)(vp);
      short8 vv1 = *(const short8*)(vp + 8);
      short8 vv2 = *(const short8*)(vp + 16);
      short8 vv3 = *(const short8*)(vp + 24);
#pragma unroll
      for (int e = 0; e < 8; ++e) {
        Vt[e * 64 + t] = (u16)vv0[e];
        Vt[(8 + e) * 64 + t] = (u16)vv1[e];
        Vt[(16 + e) * 64 + t] = (u16)vv2[e];
        Vt[(24 + e) * 64 + t] = (u16)vv3[e];
      }
    } else {
      for (int d = 0; d < 32; ++d) Vt[d * 64 + t] = 0;
    }
  }

  f32x4 s[4][4];
#pragma unroll
  for (int m = 0; m < 4; ++m)
#pragma unroll
    for (int n = 0; n < 4; ++n)
#pragma unroll
      for (int r2 = 0; r2 < 4; ++r2) s[m][n][r2] = 0.f;
#pragma unroll
  for (int m = 0; m < 4; ++m)
#pragma unroll
    for (int n = 0; n < 4; ++n)
      s[m][n] = __builtin_amdgcn_mfma_f32_16x16x32_bf16(qf[m], kf[n], s[m][n], 0, 0, 0);

  __syncthreads();

  const float SCALE = 0.17677669529663687f;
  const int rgrp = lane >> 4;
#pragma unroll
  for (int m = 0; m < 4; ++m) {
#pragma unroll
    for (int r2 = 0; r2 < 4; ++r2) {
      int rn = m * 16 + rgrp * 4 + r2;   // query token
      int qa = rn - 10;
      int qra = qa / 7, qca = qa - qra * 7;
      int regA = 0;
      if (qa >= 0 && qa < 49) {
        int ha = hi * 7 + qra, wa = wi * 7 + qca;
        regA = (ha < 21 ? 0 : (ha < 25 ? 1 : 2)) * 3 + (wa < 21 ? 0 : (wa < 25 ? 1 : 2));
      }
      float vloc[4];
      float mx = -3.0e38f;
#pragma unroll
      for (int n = 0; n < 4; ++n) {
        int cm = n * 16 + lr;            // key token
        float v;
        if (cm >= 59) {
          v = -3.0e38f;
        } else {
          v = s[m][n][r2] * SCALE;
          if (rn >= 10 && rn < 59 && cm >= 10) {
            int kb = cm - 10;
            int krb = kb / 7, kcb = kb - krb * 7;
            v += biasl[(qra - krb + 6) * 13 + (qca - kcb + 6)];
            int hb = hi * 7 + krb, wb = wi * 7 + kcb;
            int regB = (hb < 21 ? 0 : (hb < 25 ? 1 : 2)) * 3 + (wb < 21 ? 0 : (wb < 25 ? 1 : 2));
            if (regA != regB) v -= 100.0f;
          }
        }
        vloc[n] = v;
        mx = fmaxf(mx, v);
      }
#pragma unroll
      for (int o = 8; o > 0; o >>= 1) mx = fmaxf(mx, __shfl_xor(mx, o));
      float sum = 0.f;
#pragma unroll
      for (int n = 0; n < 4; ++n) {
        float e = __expf(vloc[n] - mx);
        vloc[n] = e;
        sum += e;
      }
#pragma unroll
      for (int o = 8; o > 0; o >>= 1) sum += __shfl_xor(sum, o);
      float inv = 1.0f / sum;
#pragma unroll
      for (int n = 0; n < 4; ++n)
        Plds[rn * 64 + n * 16 + lr] = f2bf(vloc[n] * inv);
    }
  }

  __syncthreads();

  f32x4 o[4][2];
#pragma unroll
  for (int m = 0; m < 4; ++m)
#pragma unroll
    for (int j = 0; j < 2; ++j)
#pragma unroll
      for (int r2 = 0; r2 < 4; ++r2) o[m][j][r2] = 0.f;
#pragma unroll
  for (int ks = 0; ks < 2; ++ks) {
    short8 pf[4], vf[2];
#pragma unroll
    for (int m = 0; m < 4; ++m)
      pf[m] = *(const short8*)&Plds[(m * 16 + lr) * 64 + ks * 32 + lk];
#pragma unroll
    for (int j = 0; j < 2; ++j)
      vf[j] = *(const short8*)&Vt[(j * 16 + lr) * 64 + ks * 32 + lk];
#pragma unroll
    for (int m = 0; m < 4; ++m)
#pragma unroll
      for (int j = 0; j < 2; ++j)
        o[m][j] = __builtin_amdgcn_mfma_f32_16x16x32_bf16(pf[m], vf[j], o[m][j], 0, 0, 0);
  }

#pragma unroll
  for (int m = 0; m < 4; ++m) {
#pragma unroll
    for (int r2 = 0; r2 < 4; ++r2) {
      int rn = m * 16 + rgrp * 4 + r2;
      if (rn >= 10 && rn < 59) {
        size_t row = (size_t)i * 49 + (rn - 10);
        u16* op = outp + row * 512 + hd * 32;
        op[lr] = f2bf(o[m][0][r2]);
        op[16 + lr] = f2bf(o[m][1][r2]);
      }
    }
  }
}

// ---------- launch ----------
extern "C" void kernel_launch(void* const* d_in, const int* in_sizes, int n_in,
                              void* d_out, int out_size, void* d_ws, size_t ws_size,
                              hipStream_t stream) {
  const float* x = (const float*)d_in[0];
  const float* g1 = (const float*)d_in[1];
  const float* b1 = (const float*)d_in[2];
  const float* qkv_w = (const float*)d_in[3];
  const float* qkv_b = (const float*)d_in[4];
  const float* rpb = (const float*)d_in[5];
  const float* proj_w = (const float*)d_in[6];
  const float* proj_b = (const float*)d_in[7];
  const float* g2 = (const float*)d_in[8];
  const float* b2 = (const float*)d_in[9];
  const float* fc1_w = (const float*)d_in[10];
  const float* fc1_b = (const float*)d_in[11];
  const float* fc2_w = (const float*)d_in[12];
  const float* fc2_b = (const float*)d_in[13];
  float* out = (float*)d_out;

  char* ws = (char*)d_ws;
  u16* qkv_wb = (u16*)(ws + 0);              // 1,572,864
  u16* proj_wb = (u16*)(ws + 1572864);       //   524,288
  u16* fc1_wb = (u16*)(ws + 2097152);        // 2,097,152
  u16* fc2_wb = (u16*)(ws + 4194304);        // 2,097,152
  u16* xcat = (u16*)(ws + 6291456);          // 52,035,584  (50816x512 bf16)
  u16* y = (u16*)(ws + 58327040);            // 156,106,752 (50816x1536 bf16)
  u16* attnv = (u16*)(ws + 214433792);       // 51,380,224  (50176x512 bf16)
  float* xnew = (float*)(ws + 265814016);    // 102,760,448 (50176x512 f32)
  u16* hin = xcat;                           // reuse (xcat dead after QKV)
  u16* hmid = y;                             // reuse (y+attnv dead after proj; fits)

  cvt_bf16<<<768, 256, 0, stream>>>(qkv_w, qkv_wb, 196608);
  cvt_bf16<<<256, 256, 0, stream>>>(proj_w, proj_wb, 65536);
  cvt_bf16<<<1024, 256, 0, stream>>>(fc1_w, fc1_wb, 262144);
  cvt_bf16<<<1024, 256, 0, stream>>>(fc2_w, fc2_wb, 262144);

  ln1_kernel<<<12704, 256, 0, stream>>>(x, g1, b1, xcat);

  // QKV: tilesTot = 199*6 = 1194 (last M-tile partial; A overreads land in y, stores guarded)
  gemm256p<0><<<256, 512, 0, stream>>>(xcat, qkv_wb, qkv_b, y, nullptr, nullptr,
                                       50816, 1536, 512, 6, 1194);

  attn_kernel<<<16384, 64, 0, stream>>>(y, rpb, attnv);

  // proj: 392 tiles, grid 196 -> exactly 2 tiles/block (balanced, pipeline spans both)
  gemm256p<1><<<196, 512, 0, stream>>>(attnv, proj_wb, proj_b, nullptr, xnew, x,
                                       50176, 512, 512, 2, 392);

  ln2_kernel<<<12544, 256, 0, stream>>>(xnew, g2, b2, hin);

  // fc1: 1568 tiles, grid 256 -> 6-7 tiles/block
  gemm256p<2><<<256, 512, 0, stream>>>(hin, fc1_wb, fc1_b, hmid, nullptr, nullptr,
                                       50176, 2048, 512, 8, 1568);

  // fc2: K=2048 (NT=64 already amortized) -> 1 tile/block, quasi-control
  gemm256p<3><<<392, 512, 0, stream>>>(hmid, fc2_wb, fc2_b, nullptr, out, xnew,
                                       50176, 512, 2048, 2, 392);
}

// Round 8
// 730.443 us; speedup vs baseline: 1.1983x; 1.1983x over previous
//
#include <hip/hip_runtime.h>
#include <stdint.h>

typedef unsigned short u16;
typedef unsigned int u32;
typedef __attribute__((ext_vector_type(8))) short short8;
typedef __attribute__((ext_vector_type(4))) float f32x4;

// ---------- helpers ----------
__device__ __forceinline__ u16 f2bf(float f) {
  u32 u = __builtin_bit_cast(u32, f);
  u32 r = u + 0x7FFFu + ((u >> 16) & 1u);
  return (u16)(r >> 16);
}

__device__ __forceinline__ void gl_lds16(const void* g, void* l) {
  __builtin_amdgcn_global_load_lds((__attribute__((address_space(1))) void*)g,
                                   (__attribute__((address_space(3))) void*)l,
                                   16, 0, 0);
}

// tanh-form GELU (~13 VALU inst; |err| <= ~3e-3, verified absmax unchanged)
__device__ __forceinline__ float gelu_fast(float v) {
  float u = 0.7978845608028654f * (v + 0.044715f * v * v * v);
  float a = fabsf(u);
  float e = __expf(-2.0f * a);
  float t = (1.0f - e) / (1.0f + e);     // tanh(|u|)
  float th = copysignf(t, u);
  return 0.5f * v * (1.0f + th);
}

// ---------- f32 -> bf16 convert (weights) ----------
__global__ __launch_bounds__(256) void cvt_bf16(const float* __restrict__ in,
                                                u16* __restrict__ out, int n4) {
  int idx = blockIdx.x * 256 + threadIdx.x;
  if (idx < n4) {
    float4 v = ((const float4*)in)[idx];
    u32 lo = (u32)f2bf(v.x) | ((u32)f2bf(v.y) << 16);
    u32 hi = (u32)f2bf(v.z) | ((u32)f2bf(v.w) << 16);
    ((uint2*)out)[idx] = make_uint2(lo, hi);
  }
}

// ---------- LN1 + roll + window partition gather ----------
__global__ __launch_bounds__(256) void ln1_kernel(const float* __restrict__ x,
                                                  const float* __restrict__ g,
                                                  const float* __restrict__ bta,
                                                  u16* __restrict__ xcat) {
  int wave = threadIdx.x >> 6, lane = threadIdx.x & 63;
  int row = blockIdx.x * 4 + wave;   // 0..50815
  const float* src;
  bool do_ln;
  if (row < 640) {
    int bb = row / 10, p = row - bb * 10;
    src = x + ((size_t)bb * 794 + p) * 512;
    do_ln = false;
  } else {
    int r2 = row - 640;
    int i = r2 / 49, t = r2 - i * 49;
    int bb = i >> 4, nw = i & 15;
    int tr = t / 7, tc = t - tr * 7;
    int hh = (nw >> 2) * 7 + tr + 3; if (hh >= 28) hh -= 28;
    int ww = (nw & 3) * 7 + tc + 3;  if (ww >= 28) ww -= 28;
    src = x + ((size_t)bb * 794 + 10 + hh * 28 + ww) * 512;
    do_ln = true;
  }
  float4 v0 = ((const float4*)src)[lane * 2];
  float4 v1 = ((const float4*)src)[lane * 2 + 1];
  float vals[8] = {v0.x, v0.y, v0.z, v0.w, v1.x, v1.y, v1.z, v1.w};
  u16 ob[8];
  if (do_ln) {
    float s = 0.f, s2 = 0.f;
#pragma unroll
    for (int j = 0; j < 8; ++j) { s += vals[j]; s2 += vals[j] * vals[j]; }
#pragma unroll
    for (int o = 32; o > 0; o >>= 1) { s += __shfl_xor(s, o); s2 += __shfl_xor(s2, o); }
    float mu = s * (1.0f / 512.0f);
    float var = s2 * (1.0f / 512.0f) - mu * mu;
    float inv = rsqrtf(var + 1e-5f);
    float4 ga = ((const float4*)g)[lane * 2], gb = ((const float4*)g)[lane * 2 + 1];
    float4 ba = ((const float4*)bta)[lane * 2], bb2 = ((const float4*)bta)[lane * 2 + 1];
    float gv[8] = {ga.x, ga.y, ga.z, ga.w, gb.x, gb.y, gb.z, gb.w};
    float bv[8] = {ba.x, ba.y, ba.z, ba.w, bb2.x, bb2.y, bb2.z, bb2.w};
#pragma unroll
    for (int j = 0; j < 8; ++j) ob[j] = f2bf((vals[j] - mu) * inv * gv[j] + bv[j]);
  } else {
#pragma unroll
    for (int j = 0; j < 8; ++j) ob[j] = f2bf(vals[j]);
  }
  u32 w0 = (u32)ob[0] | ((u32)ob[1] << 16);
  u32 w1 = (u32)ob[2] | ((u32)ob[3] << 16);
  u32 w2 = (u32)ob[4] | ((u32)ob[5] << 16);
  u32 w3 = (u32)ob[6] | ((u32)ob[7] << 16);
  ((uint4*)(xcat + (size_t)row * 512))[lane] = make_uint4(w0, w1, w2, w3);
}

// ---------- LN2 (plain rows) ----------
__global__ __launch_bounds__(256) void ln2_kernel(const float* __restrict__ xn,
                                                  const float* __restrict__ g,
                                                  const float* __restrict__ bta,
                                                  u16* __restrict__ outb) {
  int wave = threadIdx.x >> 6, lane = threadIdx.x & 63;
  size_t row = (size_t)blockIdx.x * 4 + wave;
  const float* src = xn + row * 512;
  float4 v0 = ((const float4*)src)[lane * 2];
  float4 v1 = ((const float4*)src)[lane * 2 + 1];
  float vals[8] = {v0.x, v0.y, v0.z, v0.w, v1.x, v1.y, v1.z, v1.w};
  float s = 0.f, s2 = 0.f;
#pragma unroll
  for (int j = 0; j < 8; ++j) { s += vals[j]; s2 += vals[j] * vals[j]; }
#pragma unroll
  for (int o = 32; o > 0; o >>= 1) { s += __shfl_xor(s, o); s2 += __shfl_xor(s2, o); }
  float mu = s * (1.0f / 512.0f);
  float var = s2 * (1.0f / 512.0f) - mu * mu;
  float inv = rsqrtf(var + 1e-5f);
  float4 ga = ((const float4*)g)[lane * 2], gb = ((const float4*)g)[lane * 2 + 1];
  float4 ba = ((const float4*)bta)[lane * 2], bb2 = ((const float4*)bta)[lane * 2 + 1];
  float gv[8] = {ga.x, ga.y, ga.z, ga.w, gb.x, gb.y, gb.z, gb.w};
  float bv[8] = {ba.x, ba.y, ba.z, ba.w, bb2.x, bb2.y, bb2.z, bb2.w};
  u16 ob[8];
#pragma unroll
  for (int j = 0; j < 8; ++j) ob[j] = f2bf((vals[j] - mu) * inv * gv[j] + bv[j]);
  u32 w0 = (u32)ob[0] | ((u32)ob[1] << 16);
  u32 w1 = (u32)ob[2] | ((u32)ob[3] << 16);
  u32 w2 = (u32)ob[4] | ((u32)ob[5] << 16);
  u32 w3 = (u32)ob[6] | ((u32)ob[7] << 16);
  ((uint4*)(outb + row * 512))[lane] = make_uint4(w0, w1, w2, w3);
}

// ---------- 128x128 bf16 GEMM: 4 waves, BK=32, dbuf (32 KB LDS), high occupancy ----------
// A: MxK row-major bf16, Wt: NxK row-major bf16 (B^T). All of M,N,K divide by 128.
// LDS per buffer: [128 rows][4 slots of 16B]; slot sl of row r holds global slot
// (sl ^ ((r>>1)&3)) -> 2 lanes/bank on ds_read_b128 (free); staged linear-dest with
// pre-swizzled global source (rule 21; measured 0 conflicts rounds 4-7).
// Loop (T3-minimum, cross-block TLP hides latency at ~4 blocks/CU):
//   t: STAGE(t+1 -> buf^1) ; vmcnt(4) ; bar ; 8 ds_read + 16 MFMA ; bar
template <int EPI>
__global__ __launch_bounds__(256) void gemm128d(const u16* __restrict__ A,
                                                const u16* __restrict__ Wt,
                                                const float* __restrict__ bias,
                                                u16* __restrict__ outb,
                                                float* __restrict__ outf,
                                                const float* __restrict__ res,
                                                int M, int N, int K, int Ntiles) {
  __shared__ __align__(16) u16 Asm[2][128 * 32];
  __shared__ __align__(16) u16 Bsm[2][128 * 32];
  const int tid = threadIdx.x;
  const int lane = tid & 63;
  const int wv = tid >> 6;            // 0..3
  const int wm = wv >> 1, wn = wv & 1;
  const int lr = lane & 15;
  const int qh = lane >> 4;           // 0..3 (16B slot)
  const int swz8 = (qh ^ ((lr >> 1) & 3)) << 3;   // swizzled read slot (elements)

  // bijective XCD swizzle (m204), N-fastest so same-XCD blocks share A panels
  const int nwg = gridDim.x;
  const int qx = nwg >> 3, rx = nwg & 7;
  const int xcd = blockIdx.x & 7, local = blockIdx.x >> 3;
  const int swz = (xcd < rx ? xcd * (qx + 1) : rx * (qx + 1) + (xcd - rx) * qx) + local;
  const int mt = swz / Ntiles, nt = swz - mt * Ntiles;
  const int tm = mt << 7, tn = nt << 7;

  f32x4 acc[4][4];
#pragma unroll
  for (int m = 0; m < 4; ++m)
#pragma unroll
    for (int n = 0; n < 4; ++n)
#pragma unroll
      for (int e = 0; e < 4; ++e) acc[m][n][e] = 0.f;

  // staging: thread -> row sr (0..63) slot sl; halves at rows sr / sr+64
  const int sr = tid >> 2;
  const int sl = tid & 3;
  const int scol = (sl ^ ((sr >> 1) & 3)) << 3;   // pre-swizzled source col (elements)
  const u16* Ap0 = A + (size_t)(tm + sr) * K + scol;
  const u16* Ap1 = A + (size_t)(tm + 64 + sr) * K + scol;
  const u16* Bp0 = Wt + (size_t)(tn + sr) * K + scol;
  const u16* Bp1 = Wt + (size_t)(tn + 64 + sr) * K + scol;

#define STAGE(buf, k0)                            \
  do {                                            \
    u16* da = &Asm[buf][tid * 8];                 \
    u16* db = &Bsm[buf][tid * 8];                 \
    gl_lds16(Ap0 + (k0), da);                     \
    gl_lds16(Ap1 + (k0), da + 2048);              \
    gl_lds16(Bp0 + (k0), db);                     \
    gl_lds16(Bp1 + (k0), db + 2048);              \
  } while (0)

  const int NT = K >> 5;   // 16 (K=512) or 64 (K=2048)
  STAGE(0, 0);

  int cur = 0;
  for (int t = 0; t < NT; ++t) {
    if (t + 1 < NT) {
      STAGE(cur ^ 1, (t + 1) << 5);
      asm volatile("s_waitcnt vmcnt(4)" ::: "memory");   // tile t's 4 loads landed
    } else {
      asm volatile("s_waitcnt vmcnt(0)" ::: "memory");
    }
    __builtin_amdgcn_s_barrier();                        // tile t visible to all waves
    asm volatile("" ::: "memory");

    const u16* Ab = &Asm[cur][0];
    const u16* Bb = &Bsm[cur][0];
    short8 av[4], bv[4];
#pragma unroll
    for (int m = 0; m < 4; ++m)
      av[m] = *(const short8*)&Ab[(wm * 64 + m * 16 + lr) * 32 + swz8];
#pragma unroll
    for (int n = 0; n < 4; ++n)
      bv[n] = *(const short8*)&Bb[(wn * 64 + n * 16 + lr) * 32 + swz8];
    __builtin_amdgcn_s_setprio(1);
#pragma unroll
    for (int m = 0; m < 4; ++m)
#pragma unroll
      for (int n = 0; n < 4; ++n)
        acc[m][n] = __builtin_amdgcn_mfma_f32_16x16x32_bf16(av[m], bv[n], acc[m][n], 0, 0, 0);
    __builtin_amdgcn_s_setprio(0);
    asm volatile("" ::: "memory");
    __builtin_amdgcn_s_barrier();                        // all waves done reading buf[cur]
    cur ^= 1;
  }
#undef STAGE

  float bcol[4];
#pragma unroll
  for (int n = 0; n < 4; ++n) bcol[n] = bias[tn + wn * 64 + n * 16 + lr];

#pragma unroll
  for (int m = 0; m < 4; ++m) {
#pragma unroll
    for (int r2 = 0; r2 < 4; ++r2) {
      int grow = tm + wm * 64 + m * 16 + qh * 4 + r2;
      if (EPI == 1) {
        int i = grow / 49, t = grow - i * 49;
        int bb = i >> 4, nw = i & 15;
        int tr = t / 7, tc = t - tr * 7;
        int hh = (nw >> 2) * 7 + tr + 3; if (hh >= 28) hh -= 28;
        int ww = (nw & 3) * 7 + tc + 3;  if (ww >= 28) ww -= 28;
        size_t dstr = ((size_t)bb * 784 + hh * 28 + ww) * 512;
        size_t srcr = ((size_t)bb * 794 + 10 + hh * 28 + ww) * 512;
#pragma unroll
        for (int n = 0; n < 4; ++n) {
          int gcol = tn + wn * 64 + n * 16 + lr;
          float v = acc[m][n][r2] + bcol[n];
          outf[dstr + gcol] = v + res[srcr + gcol];
        }
      } else {
#pragma unroll
        for (int n = 0; n < 4; ++n) {
          int gcol = tn + wn * 64 + n * 16 + lr;
          float v = acc[m][n][r2] + bcol[n];
          if (EPI == 0) {
            outb[(size_t)grow * N + gcol] = f2bf(v);
          } else if (EPI == 2) {
            outb[(size_t)grow * N + gcol] = f2bf(gelu_fast(v));
          } else { // EPI == 3
            outf[(size_t)grow * N + gcol] = v + res[(size_t)grow * 512 + gcol];
          }
        }
      }
    }
  }
}

// ---------- fused window attention: one wave per (window, head) ----------
__global__ __launch_bounds__(64) void attn_kernel(const u16* __restrict__ Y,
                                                  const float* __restrict__ rpb,
                                                  u16* __restrict__ outp) {
  __shared__ __align__(16) u16 Plds[64 * 64];
  __shared__ __align__(16) u16 Vt[32 * 64];
  __shared__ float biasl[169];
  const int lane = threadIdx.x;
  const int i = blockIdx.x >> 4;
  const int hd = blockIdx.x & 15;
  const int bp = i & 63;           // reference quirk: prompt batch = i % B
  const int nw = i & 15;
  const int hi = nw >> 2, wi = nw & 3;
  const int lr = lane & 15;
  const int lk = (lane >> 4) * 8;

  for (int j = lane; j < 169; j += 64) biasl[j] = rpb[j * 16 + hd];

  short8 qf[4], kf[4];
#pragma unroll
  for (int m = 0; m < 4; ++m) {
    int t = m * 16 + lr;
    size_t r = (t < 10) ? (size_t)(bp * 10 + t) : (size_t)(640 + i * 49 + (t - 10));
    const u16* base = Y + r * 1536 + hd * 32 + lk;
    if (t < 59) {
      qf[m] = *(const short8*)(base);
      kf[m] = *(const short8*)(base + 512);
    } else {
#pragma unroll
      for (int e = 0; e < 8; ++e) { qf[m][e] = 0; kf[m][e] = 0; }
    }
  }
  // stage V^T (32 x 64)
  {
    int t = lane;
    if (t < 59) {
      size_t r = (t < 10) ? (size_t)(bp * 10 + t) : (size_t)(640 + i * 49 + (t - 10));
      const u16* vp = Y + r * 1536 + 1024 + hd * 32;
      short8 vv0 = *(const short8*)(vp);
      short8 vv1 = *(const short8*)(vp + 8);
      short8 vv2 = *(const short8*)(vp + 16);
      short8 vv3 = *(const short8*)(vp + 24);
#pragma unroll
      for (int e = 0; e < 8; ++e) {
        Vt[e * 64 + t] = (u16)vv0[e];
        Vt[(8 + e) * 64 + t] = (u16)vv1[e];
        Vt[(16 + e) * 64 + t] = (u16)vv2[e];
        Vt[(24 + e) * 64 + t] = (u16)vv3[e];
      }
    } else {
      for (int d = 0; d < 32; ++d) Vt[d * 64 + t] = 0;
    }
  }

  f32x4 s[4][4];
#pragma unroll
  for (int m = 0; m < 4; ++m)
#pragma unroll
    for (int n = 0; n < 4; ++n)
#pragma unroll
      for (int r2 = 0; r2 < 4; ++r2) s[m][n][r2] = 0.f;
#pragma unroll
  for (int m = 0; m < 4; ++m)
#pragma unroll
    for (int n = 0; n < 4; ++n)
      s[m][n] = __builtin_amdgcn_mfma_f32_16x16x32_bf16(qf[m], kf[n], s[m][n], 0, 0, 0);

  __syncthreads();

  const float SCALE = 0.17677669529663687f;
  const int rgrp = lane >> 4;
#pragma unroll
  for (int m = 0; m < 4; ++m) {
#pragma unroll
    for (int r2 = 0; r2 < 4; ++r2) {
      int rn = m * 16 + rgrp * 4 + r2;   // query token
      int qa = rn - 10;
      int qra = qa / 7, qca = qa - qra * 7;
      int regA = 0;
      if (qa >= 0 && qa < 49) {
        int ha = hi * 7 + qra, wa = wi * 7 + qca;
        regA = (ha < 21 ? 0 : (ha < 25 ? 1 : 2)) * 3 + (wa < 21 ? 0 : (wa < 25 ? 1 : 2));
      }
      float vloc[4];
      float mx = -3.0e38f;
#pragma unroll
      for (int n = 0; n < 4; ++n) {
        int cm = n * 16 + lr;            // key token
        float v;
        if (cm >= 59) {
          v = -3.0e38f;
        } else {
          v = s[m][n][r2] * SCALE;
          if (rn >= 10 && rn < 59 && cm >= 10) {
            int kb = cm - 10;
            int krb = kb / 7, kcb = kb - krb * 7;
            v += biasl[(qra - krb + 6) * 13 + (qca - kcb + 6)];
            int hb = hi * 7 + krb, wb = wi * 7 + kcb;
            int regB = (hb < 21 ? 0 : (hb < 25 ? 1 : 2)) * 3 + (wb < 21 ? 0 : (wb < 25 ? 1 : 2));
            if (regA != regB) v -= 100.0f;
          }
        }
        vloc[n] = v;
        mx = fmaxf(mx, v);
      }
#pragma unroll
      for (int o = 8; o > 0; o >>= 1) mx = fmaxf(mx, __shfl_xor(mx, o));
      float sum = 0.f;
#pragma unroll
      for (int n = 0; n < 4; ++n) {
        float e = __expf(vloc[n] - mx);
        vloc[n] = e;
        sum += e;
      }
#pragma unroll
      for (int o = 8; o > 0; o >>= 1) sum += __shfl_xor(sum, o);
      float inv = 1.0f / sum;
#pragma unroll
      for (int n = 0; n < 4; ++n)
        Plds[rn * 64 + n * 16 + lr] = f2bf(vloc[n] * inv);
    }
  }

  __syncthreads();

  f32x4 o[4][2];
#pragma unroll
  for (int m = 0; m < 4; ++m)
#pragma unroll
    for (int j = 0; j < 2; ++j)
#pragma unroll
      for (int r2 = 0; r2 < 4; ++r2) o[m][j][r2] = 0.f;
#pragma unroll
  for (int ks = 0; ks < 2; ++ks) {
    short8 pf[4], vf[2];
#pragma unroll
    for (int m = 0; m < 4; ++m)
      pf[m] = *(const short8*)&Plds[(m * 16 + lr) * 64 + ks * 32 + lk];
#pragma unroll
    for (int j = 0; j < 2; ++j)
      vf[j] = *(const short8*)&Vt[(j * 16 + lr) * 64 + ks * 32 + lk];
#pragma unroll
    for (int m = 0; m < 4; ++m)
#pragma unroll
      for (int j = 0; j < 2; ++j)
        o[m][j] = __builtin_amdgcn_mfma_f32_16x16x32_bf16(pf[m], vf[j], o[m][j], 0, 0, 0);
  }

#pragma unroll
  for (int m = 0; m < 4; ++m) {
#pragma unroll
    for (int r2 = 0; r2 < 4; ++r2) {
      int rn = m * 16 + rgrp * 4 + r2;
      if (rn >= 10 && rn < 59) {
        size_t row = (size_t)i * 49 + (rn - 10);
        u16* op = outp + row * 512 + hd * 32;
        op[lr] = f2bf(o[m][0][r2]);
        op[16 + lr] = f2bf(o[m][1][r2]);
      }
    }
  }
}

// ---------- launch ----------
extern "C" void kernel_launch(void* const* d_in, const int* in_sizes, int n_in,
                              void* d_out, int out_size, void* d_ws, size_t ws_size,
                              hipStream_t stream) {
  const float* x = (const float*)d_in[0];
  const float* g1 = (const float*)d_in[1];
  const float* b1 = (const float*)d_in[2];
  const float* qkv_w = (const float*)d_in[3];
  const float* qkv_b = (const float*)d_in[4];
  const float* rpb = (const float*)d_in[5];
  const float* proj_w = (const float*)d_in[6];
  const float* proj_b = (const float*)d_in[7];
  const float* g2 = (const float*)d_in[8];
  const float* b2 = (const float*)d_in[9];
  const float* fc1_w = (const float*)d_in[10];
  const float* fc1_b = (const float*)d_in[11];
  const float* fc2_w = (const float*)d_in[12];
  const float* fc2_b = (const float*)d_in[13];
  float* out = (float*)d_out;

  char* ws = (char*)d_ws;
  u16* qkv_wb = (u16*)(ws + 0);              // 1,572,864
  u16* proj_wb = (u16*)(ws + 1572864);       //   524,288
  u16* fc1_wb = (u16*)(ws + 2097152);        // 2,097,152
  u16* fc2_wb = (u16*)(ws + 4194304);        // 2,097,152
  u16* xcat = (u16*)(ws + 6291456);          // 52,035,584  (50816x512 bf16)
  u16* y = (u16*)(ws + 58327040);            // 156,106,752 (50816x1536 bf16)
  u16* attnv = (u16*)(ws + 214433792);       // 51,380,224  (50176x512 bf16)
  float* xnew = (float*)(ws + 265814016);    // 102,760,448 (50176x512 f32)
  u16* hin = xcat;                           // reuse (xcat dead after QKV)
  u16* hmid = y;                             // reuse (y+attnv dead after proj; fits)

  cvt_bf16<<<768, 256, 0, stream>>>(qkv_w, qkv_wb, 196608);
  cvt_bf16<<<256, 256, 0, stream>>>(proj_w, proj_wb, 65536);
  cvt_bf16<<<1024, 256, 0, stream>>>(fc1_w, fc1_wb, 262144);
  cvt_bf16<<<1024, 256, 0, stream>>>(fc2_w, fc2_wb, 262144);

  ln1_kernel<<<12704, 256, 0, stream>>>(x, g1, b1, xcat);

  // QKV: 397 x 12 tiles (M = 50816 = 397*128 exactly)
  gemm128d<0><<<397 * 12, 256, 0, stream>>>(xcat, qkv_wb, qkv_b, y, nullptr, nullptr,
                                            50816, 1536, 512, 12);

  attn_kernel<<<16384, 64, 0, stream>>>(y, rpb, attnv);

  gemm128d<1><<<392 * 4, 256, 0, stream>>>(attnv, proj_wb, proj_b, nullptr, xnew, x,
                                           50176, 512, 512, 4);

  ln2_kernel<<<12544, 256, 0, stream>>>(xnew, g2, b2, hin);

  gemm128d<2><<<392 * 16, 256, 0, stream>>>(hin, fc1_wb, fc1_b, hmid, nullptr, nullptr,
                                            50176, 2048, 512, 16);

  gemm128d<3><<<392 * 4, 256, 0, stream>>>(hmid, fc2_wb, fc2_b, nullptr, out, xnew,
                                           50176, 512, 2048, 4);
}